// Round 13
// baseline (5124.389 us; speedup 1.0000x reference)
//
#include <hip/hip_runtime.h>
#include <cstdint>
#include <cstddef>

// Problem constants (B=8, N=2048, M=256)
#define NB 8
#define NN 2048
#define MM 256

typedef unsigned long long u64;

// monotone float->uint map; canonicalize -0 to +0 so float ties == key ties
__device__ __forceinline__ unsigned mapf(float f) {
  unsigned u = __float_as_uint(f + 0.f);
  return ((int)u >= 0) ? (u ^ 0x80000000u) : ~u;
}
__device__ __forceinline__ u64 shflx_u64(u64 v, int m) {
  unsigned lo = (unsigned)__shfl_xor((int)(unsigned)v, m);
  unsigned hi = (unsigned)__shfl_xor((int)(v >> 32), m);
  return ((u64)hi << 32) | lo;
}
__device__ __forceinline__ u64 agent_load(const u64* p) {
  return __hip_atomic_load(p, __ATOMIC_RELAXED, __HIP_MEMORY_SCOPE_AGENT);
}
__device__ __forceinline__ int acq_load(const int* p) {
  return __hip_atomic_load(p, __ATOMIC_ACQUIRE, __HIP_MEMORY_SCOPE_AGENT);
}

// ---------------------------------------------------------------------------
// MEGA KERNEL: lstm (blocks 0..63, one per (b,q), EXACT round-12 structure,
// 2680us verified) + 192 persistent GEMM consumer blocks streaming the keys/
// Q/S gemms on the 192 CUs the lstm leaves idle.
//
// Dependency protocol:
//  * lstm wave 1 (producer) RELEASE-stores hdone[b*8+q]=tt+1 every 64 steps
//    (agent scope release = vmcnt drain + L2 writeback; wave-granular
//    s_waitcnt covers all 32 publishing lanes' stores).
//  * consumers pull tile indices from an atomic counter (2560 tiles in
//    readiness order), ACQUIRE-poll their dependency flags (acquire at agent
//    scope invalidates L1/L2 so plain data loads are fresh), compute a
//    128x128 C-tile (1024 thr, 4x4 micro), then __syncthreads (drains all
//    waves' stores) + RELEASE-bump their done-flag.
//  * Tiles: [0,256) keys (no deps); then per i in 0..15: 16 qgemm tiles
//    (dep: hdone >= 128(i+1)) + 112 gemm2 tiles b=1..7 (dep: qdone/kdone);
//    last 256 = gemm2 b=0, guarded additionally by "all qgemm of Hall batch
//    i>>1 complete" because Hall (h trajectory) lives in d_out = exactly
//    S[0] and those tiles overwrite it.
//  * Deadlock-impossible by capacity: 256 blocks x 1024 thr = 1 block/CU at
//    <=128 VGPR -> all blocks co-resident regardless of dispatch order;
//    consumers wait on DATA only, producers never wait on consumers.
//  * select/softmax stay as separate kernels (serial S-row dependence).
// ---------------------------------------------------------------------------
__global__ __launch_bounds__(1024) void mega_kernel(
    const float* __restrict__ z_g, const float* __restrict__ dec,
    const float* __restrict__ h0, const float* __restrict__ w_ih,
    const float* __restrict__ w_hh, const float* __restrict__ b_ih,
    const float* __restrict__ b_hh, const float* __restrict__ emb,
    const float* __restrict__ Wk, const float* __restrict__ bk,
    const float* __restrict__ Wq, const float* __restrict__ bq,
    float* __restrict__ keys, float* __restrict__ Qbuf,
    float* __restrict__ out, u64* __restrict__ Pbuf, int* __restrict__ F)
{
  __shared__ __align__(16) float hbuf[256];
  __shared__ __align__(16) float act[128];
  __shared__ __align__(16) float As[32][132];
  __shared__ __align__(16) float Bs[32][132];
  __shared__ int s_tile;

  const int tid = threadIdx.x;
  float* Hall = out;                       // h trajectory borrows d_out (=S[0])

  if (blockIdx.x < 64) {
    // =================== LSTM ROLE (round-12 verified) ===================
    const int b = blockIdx.x & 7;
    const int q = blockIdx.x >> 3;
    const int w = tid >> 6;
    const int lane = tid & 63;
    const int rr = lane >> 3;
    const int c8 = lane & 7;
    const int lr = 8 * w + rr;
    const int g = lr >> 5;
    const int m = lr & 31;
    const int grow = g * 256 + 32 * q + m;

    float wreg[32];
    {
      const float* wr = w_hh + (size_t)grow * MM + 32 * c8;
      #pragma unroll
      for (int jj = 0; jj < 8; ++jj) {
        float4 v = *(const float4*)(wr + 4 * ((jj + c8) & 7));
        wreg[4 * jj + 0] = v.x; wreg[4 * jj + 1] = v.y;
        wreg[4 * jj + 2] = v.z; wreg[4 * jj + 3] = v.w;
      }
    }
    float xb;
    {
      const float* wr = w_ih + (size_t)grow * MM + 32 * c8;
      float p = 0.f;
      #pragma unroll
      for (int i = 0; i < 8; ++i) {
        float4 wv = *(const float4*)(wr + 4 * i);
        float4 dv = *(const float4*)(dec + 32 * c8 + 4 * i);
        p += wv.x * dv.x + wv.y * dv.y + wv.z * dv.z + wv.w * dv.w;
      }
      p += __shfl_xor(p, 1); p += __shfl_xor(p, 2); p += __shfl_xor(p, 4);
      xb = p + b_ih[grow] + b_hh[grow];
    }

    float c_my = 0.f;
    if (w == 1 && lane < 32) c_my = z_g[b * MM + 32 * q + lane];
    if (tid < 256) hbuf[tid] = h0[tid];

    u64* Pb = Pbuf + (size_t)b * 512;
    float* Hb = Hall + (size_t)b * NN * MM + 32 * q;
    int* hflag = F + 8 + (b << 3) + q;

    const bool own0 = ((lane >> 5) + 0) == q;
    const bool own1 = ((lane >> 5) + 2) == q;
    const bool own2 = ((lane >> 5) + 4) == q;
    const bool own3 = ((lane >> 5) + 6) == q;

    for (int tt = 0; tt < NN; ++tt) {
      if (tt > 0 && w == 0) {
        const u64* pa = Pb + ((tt & 1) << 8);
        const unsigned tg = (unsigned)tt;
        u64 a0, a1, a2, a3;
        for (;;) {
          a0 = agent_load(pa + lane);
          a1 = agent_load(pa + 64 + lane);
          a2 = agent_load(pa + 128 + lane);
          a3 = agent_load(pa + 192 + lane);
          const bool ok = (own0 | ((unsigned)(a0 >> 32) == tg))
                        & (own1 | ((unsigned)(a1 >> 32) == tg))
                        & (own2 | ((unsigned)(a2 >> 32) == tg))
                        & (own3 | ((unsigned)(a3 >> 32) == tg));
          if (__all((int)ok)) break;
        }
        if (!own0) hbuf[lane]       = __uint_as_float((unsigned)a0);
        if (!own1) hbuf[64 + lane]  = __uint_as_float((unsigned)a1);
        if (!own2) hbuf[128 + lane] = __uint_as_float((unsigned)a2);
        if (!own3) hbuf[192 + lane] = __uint_as_float((unsigned)a3);
      }
      __syncthreads();                                  // BAR A

      const float4* h4 = (const float4*)hbuf;
      float a0 = 0.f, a1 = 0.f, a2 = 0.f, a3 = 0.f;
      #pragma unroll
      for (int jj = 0; jj < 8; ++jj) {
        float4 hv = h4[8 * c8 + ((jj + c8) & 7)];
        a0 = fmaf(hv.x, wreg[4 * jj + 0], a0);
        a1 = fmaf(hv.y, wreg[4 * jj + 1], a1);
        a2 = fmaf(hv.z, wreg[4 * jj + 2], a2);
        a3 = fmaf(hv.w, wreg[4 * jj + 3], a3);
      }
      float s = (a0 + a1) + (a2 + a3);
      s += __shfl_xor(s, 1); s += __shfl_xor(s, 2); s += __shfl_xor(s, 4);
      const float gsum = s + xb;

      float a;
      if ((w >> 2) == 2) { const float e = __expf(-2.f * gsum); a = 2.f / (1.f + e) - 1.f; }
      else               { a = 1.f / (1.f + __expf(-gsum)); }
      if (c8 == 0) act[lr] = a;
      __syncthreads();                                  // BAR B

      if (w == 1 && lane < 32) {
        const float i_g = act[lane], f_g = act[32 + lane];
        const float g_g = act[64 + lane], o_g = act[96 + lane];
        c_my = f_g * c_my + i_g * g_g;
        const float e2 = __expf(-2.f * c_my);
        const float hn = o_g * (2.f / (1.f + e2) - 1.f);
        const u64 pk = ((u64)(unsigned)(tt + 1) << 32) | (u64)__float_as_uint(hn);
        __hip_atomic_store(Pb + (((tt + 1) & 1) << 8) + 32 * q + lane, pk,
                           __ATOMIC_RELAXED, __HIP_MEMORY_SCOPE_AGENT);
        hbuf[32 * q + lane] = hn;
        Hb[(size_t)tt * MM + lane] = hn;
        // progress publish (release: drains this wave's Hall stores and
        // writes back L2 so consumers' acquire sees them)
        if (lane == 0 && (tt & 63) == 63)
          __hip_atomic_store(hflag, tt + 1, __ATOMIC_RELEASE,
                             __HIP_MEMORY_SCOPE_AGENT);
      }
    }
    if (w == 1 && lane == 0)
      __hip_atomic_store(hflag, NN, __ATOMIC_RELEASE, __HIP_MEMORY_SCOPE_AGENT);
    return;
  }

  // ==================== CONSUMER ROLE (persistent) =====================
  int* wcnt  = F;          // work counter
  int* hdone = F + 8;      // [64]  (b*8+q) -> steps completed
  int* qdone = F + 80;     // [128] (b*16+i) -> col-tiles done (target 2)
  int* kdone = F + 208;    // [128] keys row-panel -> col-tiles done (target 2)

  for (;;) {
    __syncthreads();
    if (tid == 0) s_tile = atomicAdd(wcnt, 1);
    __syncthreads();
    const int tile = s_tile;
    if (tile >= 2560) return;

    const float *Ab, *Bb, *bias;
    float* Cb; int ldc; int* bumpf = nullptr;

    if (tile < 256) {
      // keys: [16384,256] = emb @ Wk^T + bk   (no deps)
      const int rp = tile >> 1, j = tile & 1;
      Ab = emb + (size_t)rp * 128 * MM;
      Bb = Wk + (size_t)j * 128 * MM;
      bias = bk + j * 128;
      Cb = keys + (size_t)rp * 128 * MM + j * 128;
      ldc = MM;
      bumpf = &kdone[rp];
    } else if (tile < 2304) {
      const int t2 = tile - 256;
      const int i = t2 >> 7;         // t-panel 0..15
      const int r = t2 & 127;
      if (r < 16) {
        // qgemm: Q[b] panel i = Hall[b][128i..] @ Wq^T + bq
        const int b = r >> 1, j = r & 1;
        if (tid == 0) {
          const int need = 128 * (i + 1);
          for (int qq = 0; qq < 8; ++qq)
            while (acq_load(&hdone[b * 8 + qq]) < need)
              __builtin_amdgcn_s_sleep(64);
        }
        __syncthreads();
        Ab = Hall + ((size_t)b * NN + i * 128) * MM;
        Bb = Wq + (size_t)j * 128 * MM;
        bias = bq + j * 128;
        Cb = Qbuf + ((size_t)b * NN + i * 128) * MM + j * 128;
        ldc = MM;
        bumpf = &qdone[b * 16 + i];
      } else {
        // gemm2 (b=1..7): S[b] tile (i,j) = Q[b]p(i) @ keys[b]p(j)^T
        const int rrr = r - 16;
        const int b = 1 + (rrr >> 4), j = rrr & 15;
        if (tid == 0) {
          while (acq_load(&qdone[b * 16 + i]) < 2) __builtin_amdgcn_s_sleep(64);
          while (acq_load(&kdone[b * 16 + j]) < 2) __builtin_amdgcn_s_sleep(64);
        }
        __syncthreads();
        Ab = Qbuf + ((size_t)b * NN + i * 128) * MM;
        Bb = keys + ((size_t)b * NN + j * 128) * MM;
        bias = nullptr;
        Cb = out + (size_t)b * NN * NN + (size_t)(i * 128) * NN + j * 128;
        ldc = NN;
      }
    } else {
      // gemm2 b=0 (LAST): overwrites Hall (d_out = S[0]); extra guard:
      // every qgemm of the clobbered Hall batch (i>>1) must be complete.
      const int t3 = tile - 2304;
      const int i = t3 >> 4, j = t3 & 15;
      const int bp = i >> 1;
      if (tid == 0) {
        for (int t = 0; t < 16; ++t)
          while (acq_load(&qdone[bp * 16 + t]) < 2) __builtin_amdgcn_s_sleep(64);
        while (acq_load(&qdone[i]) < 2) __builtin_amdgcn_s_sleep(64);
        while (acq_load(&kdone[j]) < 2) __builtin_amdgcn_s_sleep(64);
      }
      __syncthreads();
      Ab = Qbuf + (size_t)(i * 128) * MM;
      Bb = keys + (size_t)(j * 128) * MM;
      bias = nullptr;
      Cb = out + (size_t)(i * 128) * NN + j * 128;
      ldc = NN;
    }

    // ---- 128x128 C-tile, K=256, 1024 threads, 4x4 micro-tile ----
    const int tx = tid & 31;
    const int ty = (tid >> 5) & 31;
    float acc[4][4];
    #pragma unroll
    for (int ii = 0; ii < 4; ++ii)
      #pragma unroll
      for (int jj = 0; jj < 4; ++jj) acc[ii][jj] = 0.f;

    const int sr = tid >> 3;
    const int sc = (tid & 7) << 2;
    for (int k0 = 0; k0 < MM; k0 += 32) {
      float4 va = *(const float4*)(Ab + (size_t)sr * MM + k0 + sc);
      float4 vb = *(const float4*)(Bb + (size_t)sr * MM + k0 + sc);
      __syncthreads();
      As[sc + 0][sr] = va.x; As[sc + 1][sr] = va.y;
      As[sc + 2][sr] = va.z; As[sc + 3][sr] = va.w;
      Bs[sc + 0][sr] = vb.x; Bs[sc + 1][sr] = vb.y;
      Bs[sc + 2][sr] = vb.z; Bs[sc + 3][sr] = vb.w;
      __syncthreads();
      #pragma unroll
      for (int kk = 0; kk < 32; ++kk) {
        float4 a4 = *(const float4*)&As[kk][ty * 4];
        float4 b4 = *(const float4*)&Bs[kk][tx * 4];
        const float av[4] = {a4.x, a4.y, a4.z, a4.w};
        const float bv[4] = {b4.x, b4.y, b4.z, b4.w};
        #pragma unroll
        for (int ii = 0; ii < 4; ++ii)
          #pragma unroll
          for (int jj = 0; jj < 4; ++jj)
            acc[ii][jj] = fmaf(av[ii], bv[jj], acc[ii][jj]);
      }
    }
    #pragma unroll
    for (int ii = 0; ii < 4; ++ii) {
      float4 o;
      float* op = &o.x;
      #pragma unroll
      for (int jj = 0; jj < 4; ++jj) {
        float v = acc[ii][jj];
        if (bias) v += bias[tx * 4 + jj];
        op[jj] = v;
      }
      *(float4*)(Cb + (size_t)(ty * 4 + ii) * ldc + tx * 4) = o;
    }

    __syncthreads();   // vmcnt(0) drain of ALL waves' stores before release
    if (bumpf && tid == 0)
      __hip_atomic_fetch_add(bumpf, 1, __ATOMIC_RELEASE,
                             __HIP_MEMORY_SCOPE_AGENT);
  }
}

// ---------------------------------------------------------------------------
// Phase D: exact greedy masked argmax chain, one block (512 thr) per batch.
// (round-9/12 verified form)
// ---------------------------------------------------------------------------
__global__ __launch_bounds__(512) void select_block(
    const float* __restrict__ S, int* __restrict__ sel)
{
  const int b = blockIdx.x;
  const int tid = threadIdx.x;
  const int w = tid >> 6;          // 0..7
  const int lane = tid & 63;
  const float* Sb = S + (size_t)b * NN * NN + 4 * tid;
  int* selb = sel + b * NN;

  __shared__ u64 partial[2][8];

  for (int i = tid; i < NN; i += 512) selb[i] = 0x7fffffff;
  __syncthreads();

  unsigned mybits = 0;                 // used flags for my 4 columns
  const unsigned base = 2047u - 4u * (unsigned)tid;

  auto stepf = [&](float4 v, int t) {
    u64 k0 = (mybits & 1u) ? 0 : (((u64)mapf(v.x) << 32) | (base - 0u));
    u64 k1 = (mybits & 2u) ? 0 : (((u64)mapf(v.y) << 32) | (base - 1u));
    u64 k2 = (mybits & 4u) ? 0 : (((u64)mapf(v.z) << 32) | (base - 2u));
    u64 k3 = (mybits & 8u) ? 0 : (((u64)mapf(v.w) << 32) | (base - 3u));
    u64 k = k0 > k1 ? k0 : k1;
    if (k2 > k) k = k2;
    if (k3 > k) k = k3;
    #pragma unroll
    for (int off = 1; off < 64; off <<= 1) {
      u64 o = shflx_u64(k, off);
      if (o > k) k = o;
    }
    if (lane == 0) partial[t & 1][w] = k;
    __syncthreads();
    u64 pk = partial[t & 1][lane & 7];
    #pragma unroll
    for (int off = 1; off < 8; off <<= 1) {
      u64 o = shflx_u64(pk, off);
      if (o > pk) pk = o;
    }
    const int idx = 2047 - (int)(pk & 0x7ff);
    if ((idx >> 2) == tid) mybits |= 1u << (idx & 3);
    if (tid == 0) selb[idx] = t;
  };

  float4 r0 = *(const float4*)(Sb + (size_t)0 * NN);
  float4 r1 = *(const float4*)(Sb + (size_t)1 * NN);
  float4 r2 = *(const float4*)(Sb + (size_t)2 * NN);
  float4 r3 = *(const float4*)(Sb + (size_t)3 * NN);
  for (int t = 0; t < NN; t += 4) {
    const size_t p4 = (size_t)((t + 4 < NN) ? t + 4 : NN - 1) * NN;
    const size_t p5 = (size_t)((t + 5 < NN) ? t + 5 : NN - 1) * NN;
    const size_t p6 = (size_t)((t + 6 < NN) ? t + 6 : NN - 1) * NN;
    const size_t p7 = (size_t)((t + 7 < NN) ? t + 7 : NN - 1) * NN;
    stepf(r0, t);     r0 = *(const float4*)(Sb + p4);
    stepf(r1, t + 1); r1 = *(const float4*)(Sb + p5);
    stepf(r2, t + 2); r2 = *(const float4*)(Sb + p6);
    stepf(r3, t + 3); r3 = *(const float4*)(Sb + p7);
  }
}

// ---------------------------------------------------------------------------
// Phase E: in-place masked softmax per row. Row t masks n iff sel[n] < t.
// ---------------------------------------------------------------------------
__global__ __launch_bounds__(256) void softmax_kernel(
    float* __restrict__ out, const int* __restrict__ sel)
{
  const int t = blockIdx.x;
  const int b = blockIdx.y;
  const int tid = threadIdx.x;
  float* row = out + ((size_t)b * NN + t) * NN;
  const int* selb = sel + b * NN;
  __shared__ float red[8];

  float v[8];
  int sl[8];
  #pragma unroll
  for (int u = 0; u < 2; ++u) {
    float4 f = *(const float4*)(row + u * 1024 + tid * 4);
    int4 s4 = *(const int4*)(selb + u * 1024 + tid * 4);
    v[u * 4 + 0] = f.x; v[u * 4 + 1] = f.y; v[u * 4 + 2] = f.z; v[u * 4 + 3] = f.w;
    sl[u * 4 + 0] = s4.x; sl[u * 4 + 1] = s4.y; sl[u * 4 + 2] = s4.z; sl[u * 4 + 3] = s4.w;
  }

  float mx = -3.0e38f;
  #pragma unroll
  for (int e = 0; e < 8; ++e)
    if (sl[e] >= t) mx = fmaxf(mx, v[e]);
  #pragma unroll
  for (int off = 1; off < 64; off <<= 1) mx = fmaxf(mx, __shfl_xor(mx, off));
  if ((tid & 63) == 0) red[tid >> 6] = mx;
  __syncthreads();
  mx = fmaxf(fmaxf(red[0], red[1]), fmaxf(red[2], red[3]));

  float e8[8];
  float sum = 0.f;
  #pragma unroll
  for (int e = 0; e < 8; ++e) {
    float ex = (sl[e] >= t) ? __expf(v[e] - mx) : 0.f;
    e8[e] = ex;
    sum += ex;
  }
  #pragma unroll
  for (int off = 1; off < 64; off <<= 1) sum += __shfl_xor(sum, off);
  if ((tid & 63) == 0) red[4 + (tid >> 6)] = sum;
  __syncthreads();
  sum = red[4] + red[5] + red[6] + red[7];
  const float inv = 1.f / sum;

  #pragma unroll
  for (int u = 0; u < 2; ++u) {
    float4 o;
    o.x = e8[u * 4 + 0] * inv; o.y = e8[u * 4 + 1] * inv;
    o.z = e8[u * 4 + 2] * inv; o.w = e8[u * 4 + 3] * inv;
    *(float4*)(row + u * 1024 + tid * 4) = o;
  }
}

// ---------------------------------------------------------------------------
// ws layout (floats): keys[4194304] | Q[4194304] | Pbuf(u64 4096 = 32KB) |
//                     flags[512 ints] | sel[16384]   ~ 33.7 MB
// Hall (h trajectory) borrows d_out (= S[0] exactly); gemm2 b=0 tiles are
// scheduled last with a consumed-Hall guard.
// ---------------------------------------------------------------------------
extern "C" void kernel_launch(void* const* d_in, const int* in_sizes, int n_in,
                              void* d_out, int out_size, void* d_ws, size_t ws_size,
                              hipStream_t stream)
{
  (void)in_sizes; (void)n_in; (void)out_size; (void)ws_size;
  const float* emb  = (const float*)d_in[0];
  const float* z_g  = (const float*)d_in[1];
  const float* dec  = (const float*)d_in[2];
  const float* h0   = (const float*)d_in[3];
  const float* w_ih = (const float*)d_in[4];
  const float* w_hh = (const float*)d_in[5];
  const float* b_ih = (const float*)d_in[6];
  const float* b_hh = (const float*)d_in[7];
  const float* Wq   = (const float*)d_in[8];
  const float* bq   = (const float*)d_in[9];
  const float* Wk   = (const float*)d_in[10];
  const float* bk   = (const float*)d_in[11];
  float* out = (float*)d_out;
  float* ws  = (float*)d_ws;

  float* keys  = ws;
  float* Q     = ws + 4194304;
  u64*   Pbuf  = (u64*)(ws + 8388608);    // 4096 u64 = 32 KB (packed)
  int*   F     = (int*)(ws + 8396800);    // wcnt|hdone[64]|qdone[128]|kdone[128]
  int*   sel   = (int*)(ws + 8397312);

  // zero exchange tags + all progress flags (tag 0 / count 0 never awaited)
  hipMemsetAsync(Pbuf, 0, 34816, stream);

  mega_kernel<<<256, 1024, 0, stream>>>(
      z_g, dec, h0, w_ih, w_hh, b_ih, b_hh,
      emb, Wk, bk, Wq, bq, keys, Q, out, Pbuf, F);

  select_block<<<NB, 512, 0, stream>>>(out, sel);

  softmax_kernel<<<dim3(NN, NB), 256, 0, stream>>>(out, sel);
}